// Round 7
// baseline (12083.118 us; speedup 1.0000x reference)
//
#include <hip/hip_runtime.h>

#define DIM   256
#define RANK  64
#define NSEG0 192                 // dim - rank = shortest segment
#define N0    14304               // sum_{j=0}^{63} (192+j) complex pairs per batch
#define NW    8                   // waves per block (scan bands of 8)
#define TILE  8                   // rows per staged trig tile
#define NBUF  3                   // trig tile buffers
#define HSTEP (DIM / 2)           // 128 row-pairs
#define NMACRO 34                 // 34*4 = 136 substeps >= 135
#define ROWB  (64 * 16)           // bytes per trig row

// Raw barrier without vmcnt drain (R2: neutral vs __syncthreads, kept so the
// theta prefetch can stay in flight). lgkmcnt(0) orders LDS write->bar->read.
#define BAR() asm volatile("s_waitcnt lgkmcnt(0)\n\ts_barrier" ::: "memory")

// broadcast lane L of a per-lane VGPR to a wave-uniform (SGPR) float
#define RL(v, L) __uint_as_float(__builtin_amdgcn_readlane(__float_as_uint(v), (L)))

// Scalar complex Givens-with-phase rotation, 16 VALU ops (2cy each) — same
// VALU-cycle cost as the old 8x v_pk form, but trig operands are WAVE-UNIFORM
// floats the compiler keeps in SGPRs (1 scalar operand per FMA — legal).
// Row-state behavior is encoded in the trig VALUES staged per (row, seg):
//   (ct,st,er,ei) = real trig     -> rotation
//   (1, 0, 1, 0)                  -> V'=A, A'=V      (deposit row, bit-exact)
//   (0,-1, 1, 0)                  -> V'=V, A'=-A     (dead row; A dead too)
// Lane inactivity (c < 64-j) is an exec guard at the call site (as R6).
__device__ __forceinline__ void rot_s(float ct, float st, float er, float ei,
                                      float& Vx, float& Vy, float& Ax, float& Ay)
{
    const float ux = ct * Ax - st * Vx;      // u  = ct*A - st*V
    const float uy = ct * Ay - st * Vy;
    const float px = ct * Vx + st * Ax;      // pp = ct*V + st*A
    const float py = ct * Vy + st * Ay;
    Vx = er * ux + ei * uy;                  // V' = u * conj(e)
    Vy = er * uy - ei * ux;
    Ax = er * px - ei * py;                  // A' = pp * e
    Ay = er * py + ei * px;
}

// launch_bounds(512, 7): VGPR cap 73 — R4 showed cap 64 makes the allocator
// SPILL to scratch (FETCH 62->510 MB, +57%). Demand here ~40 VGPR; no spill.
__global__ __launch_bounds__(64 * NW, 7)
void stiefel_pipe(const float* __restrict__ theta, float* __restrict__ out,
                  long long out_limit)
{
    const int b   = blockIdx.x;
    const int tid = threadIdx.x;
    const int w   = __builtin_amdgcn_readfirstlane(tid >> 6);  // band 0..7 (SGPR)
    const int c   = tid & 63;                                  // column lane

    const float2* tb = (const float2*)theta + (size_t)b * N0;  // (t,p) pairs
    const long long obase = (long long)b * (DIM * RANK);

    // 3*8*64*16 = 24576 B  +  7*2*64*16 = 14336 B  -> 38912 B (4 blocks/CU)
    __shared__ float4 trigT[NBUF][TILE][64];
    __shared__ float4 pipe[NW - 1][2][64];    // [boundary][pair parity][col] = {V0,V1}

    const int jbase = 8 * w;

    float Ax[8], Ay[8];
    #pragma unroll
    for (int k = 0; k < 8; ++k) { Ax[k] = 0.f; Ay[k] = 0.f; }

    // hoisted per-scan activity predicates (v_cmp once, SGPR-pair masks)
    bool act[8];
    #pragma unroll
    for (int k = 0; k < 8; ++k) act[k] = (c >= 64 - (jbase + k));  // j=0 -> none

    // per-lane trig-gather byte offset within a row-pair window:
    //   lane l -> comp (l&3), scan (l>>2)&7, row (l>>5)
    // (2 lanes/bank aliasing across the row halves — free per m136)
    const int gath = ((c >> 5) << 10) + (jbase << 4) + ((c & 31) << 2);

    // staging ownership: thread -> (row rS of tile, segment jS); 512 thr = 8x64
    const int jS   = c;
    const int rS   = w;
    const int offS = NSEG0 * jS + ((jS * (jS - 1)) >> 1);
    const int lenS = NSEG0 + jS;

    // rowJ generator state (band 0; lane c <-> segment 63-c)
    const int gseg = 63 - c;
    float S = 1.f, Er = 1.f, Ei = 0.f;

    // prefetch theta for tile 0 (row rS < 192 always valid)
    float2 pf = tb[offS + rS];

    const char* ldsT = (const char*)trigT;

    #pragma unroll 1
    for (int Sm = 0; Sm < NMACRO; ++Sm) {
        // ---- stage one 8-row trig tile per macro-step, from prefetched regs ----
        if (Sm < 32) {
            const int i = (Sm << 3) + rS;          // global row this thread stages
            float4 val;
            if (i < lenS) {
                val = make_float4(__cosf(pf.x), __sinf(pf.x),
                                  __cosf(pf.y), __sinf(pf.y));
            } else if (i == lenS) {
                val = make_float4(1.f, 0.f, 1.f, 0.f);     // deposit row
            } else {
                val = make_float4(0.f, -1.f, 1.f, 0.f);    // dead row
            }
            trigT[Sm % NBUF][rS][jS] = val;
            const int i2 = i + TILE;               // prefetch next tile's theta
            if (i2 < lenS && Sm + 1 < 32) pf = tb[offS + i2];
        }

        #pragma unroll
        for (int u = 0; u < 4; ++u) {
            const int s = (Sm << 2) + u;
            BAR();                                 // the step boundary

            const int q = s - w;                   // this band's row-pair index
            if (q >= 0 && q < HSTEP) {
                const int i0 = q << 1;             // even row of the pair
                const int rowbase =
                    ((((i0 >> 3) % NBUF) * TILE + (i0 & 7))) * ROWB;

                // ---- single gather read: all 64 trig floats this wave needs ----
                const float tvf = *(const float*)(ldsT + rowbase + gath);

                // ---- values entering this band (2 rows) ----
                float V0x, V0y, V1x, V1y;
                if (w == 0) {
                    const char* gp = ldsT + (rowbase + (gseg << 4));
                    const float4 g0 = *(const float4*)gp;
                    const float4 g1 = *(const float4*)(gp + ROWB);
                    {   // row i0
                        const float Fr = Er * g0.z + Ei * g0.w;   // E * conj(e_i)
                        const float Fi = Ei * g0.z - Er * g0.w;
                        const float amp = g0.x * S;
                        V0x = amp * Fr; V0y = amp * Fi;
                        S *= g0.y;
                        const float nEr = Er * g0.z - Ei * g0.w;  // E *= e_i
                        const float nEi = Ei * g0.z + Er * g0.w;
                        Er = nEr; Ei = nEi;
                    }
                    {   // row i0+1
                        const float Fr = Er * g1.z + Ei * g1.w;
                        const float Fi = Ei * g1.z - Er * g1.w;
                        const float amp = g1.x * S;
                        V1x = amp * Fr; V1y = amp * Fi;
                        S *= g1.y;
                        const float nEr = Er * g1.z - Ei * g1.w;
                        const float nEi = Ei * g1.z + Er * g1.w;
                        Er = nEr; Ei = nEi;
                    }
                } else {
                    const float4 pv = pipe[w - 1][q & 1][c];
                    V0x = pv.x; V0y = pv.y; V1x = pv.z; V1y = pv.w;
                }

                // ---- 8 scans x 2 rows: trig via readlane -> SGPR operands ----
                #pragma unroll
                for (int k = 0; k < 8; ++k) {
                    if (act[k]) {
                        const float ct0 = RL(tvf, 4 * k + 0);
                        const float st0 = RL(tvf, 4 * k + 1);
                        const float cp0 = RL(tvf, 4 * k + 2);
                        const float sp0 = RL(tvf, 4 * k + 3);
                        rot_s(ct0, st0, cp0, sp0, V0x, V0y, Ax[k], Ay[k]);
                        const float ct1 = RL(tvf, 32 + 4 * k + 0);
                        const float st1 = RL(tvf, 32 + 4 * k + 1);
                        const float cp1 = RL(tvf, 32 + 4 * k + 2);
                        const float sp1 = RL(tvf, 32 + 4 * k + 3);
                        rot_s(ct1, st1, cp1, sp1, V1x, V1y, Ax[k], Ay[k]);
                    }
                }

                // ---- pass pair to next band / emit real parts ----
                if (w < NW - 1) {
                    pipe[w][q & 1][c] = make_float4(V0x, V0y, V1x, V1y);
                } else {
                    const long long oidx = obase + (long long)i0 * RANK + c;
                    if (oidx < out_limit)        out[oidx]        = V0x;
                    if (oidx + RANK < out_limit) out[oidx + RANK] = V1x;
                }
            }
        }
    }
}

extern "C" void kernel_launch(void* const* d_in, const int* in_sizes, int n_in,
                              void* d_out, int out_size, void* d_ws, size_t ws_size,
                              hipStream_t stream)
{
    const float* theta = (const float*)d_in[0];
    float* out = (float*)d_out;
    const int batch = in_sizes[0] / (2 * N0);        // 1024 for this problem
    if (batch <= 0) return;

    stiefel_pipe<<<batch, 64 * NW, 0, stream>>>(theta, out, (long long)out_size);
}

// Round 8
// 824.921 us; speedup vs baseline: 14.6476x; 14.6476x over previous
//
#include <hip/hip_runtime.h>

#define DIM   256
#define RANK  64
#define NSEG0 192                 // dim - rank = shortest segment
#define N0    14304               // sum_{j=0}^{63} (192+j) complex pairs per batch
#define NW    8                   // waves per block (scan bands of 8)
#define TILE  8                   // rows per staged trig tile
#define NBUF  3                   // trig tile buffers
#define HSTEP (DIM / 2)           // 128 row-pairs
#define NMACRO 34                 // 34*4 = 136 substeps >= 135
#define ROWB  (64 * 16)           // bytes per trig row

// Raw barrier without vmcnt drain (R2: neutral vs __syncthreads, kept so the
// theta prefetch can stay in flight). lgkmcnt(0) orders LDS write->bar->read.
#define BAR() asm volatile("s_waitcnt lgkmcnt(0)\n\ts_barrier" ::: "memory")

// broadcast lane L of a per-lane VGPR to a wave-uniform (SGPR) float.
// MUST only be used in wave-uniform control flow (R7 post-mortem: convergent
// readlane under a divergent branch blocked unrolling -> scratch, 50 GB/disp).
#define RL(v, L) __uint_as_float(__builtin_amdgcn_readlane(__float_as_uint(v), (L)))

// Scalar complex Givens-with-phase rotation, 16 FMA-class VALU ops (2 cyc
// each, same total as the pk form) with WAVE-UNIFORM trig operands: the
// compiler keeps them in SGPRs and each mul/fma reads at most one SGPR.
// Row-state behavior is encoded in the trig VALUES staged per (row, seg):
//   (ct,st,er,ei) = real trig     -> rotation
//   (1, 0, 1, 0)                  -> V'=A, A'=V      (deposit row, bit-exact)
//   (0,-1, 1, 0)                  -> V'=V, A'=-A     (dead row; A dead too)
// Lane inactivity (c < 64-j) is an exec guard at the call site (as R6).
__device__ __forceinline__ void rot_s(float ct, float st, float er, float ei,
                                      float& Vx, float& Vy, float& Ax, float& Ay)
{
    const float ux = ct * Ax - st * Vx;      // u  = ct*A - st*V
    const float uy = ct * Ay - st * Vy;
    const float px = ct * Vx + st * Ax;      // pp = ct*V + st*A
    const float py = ct * Vy + st * Ay;
    Vx = er * ux + ei * uy;                  // V' = u * conj(e)
    Vy = er * uy - ei * ux;
    Ax = er * px - ei * py;                  // A' = pp * e
    Ay = er * py + ei * px;
}

// One scan k: readlanes in UNIFORM control flow, rotations exec-guarded.
// Literal lane indices + named scalars -> no runtime indexing anywhere.
#define STEPK(k)                                                          \
  {                                                                       \
    const float ct0 = RL(tvf, 4*(k) + 0);                                 \
    const float st0 = RL(tvf, 4*(k) + 1);                                 \
    const float cp0 = RL(tvf, 4*(k) + 2);                                 \
    const float sp0 = RL(tvf, 4*(k) + 3);                                 \
    const float ct1 = RL(tvf, 32 + 4*(k) + 0);                            \
    const float st1 = RL(tvf, 32 + 4*(k) + 1);                            \
    const float cp1 = RL(tvf, 32 + 4*(k) + 2);                            \
    const float sp1 = RL(tvf, 32 + 4*(k) + 3);                            \
    if (act##k) {                                                         \
      rot_s(ct0, st0, cp0, sp0, V0x, V0y, Ax##k, Ay##k);                  \
      rot_s(ct1, st1, cp1, sp1, V1x, V1y, Ax##k, Ay##k);                  \
    }                                                                     \
  }

// launch_bounds(512, 7): VGPR cap 73 — R4 showed cap 64 makes the allocator
// SPILL to scratch (FETCH 62->510 MB, +57%). Demand here ~44 VGPR; no spill.
__global__ __launch_bounds__(64 * NW, 7)
void stiefel_pipe(const float* __restrict__ theta, float* __restrict__ out,
                  long long out_limit)
{
    const int b   = blockIdx.x;
    const int tid = threadIdx.x;
    const int w   = __builtin_amdgcn_readfirstlane(tid >> 6);  // band 0..7 (SGPR)
    const int c   = tid & 63;                                  // column lane

    const float2* tb = (const float2*)theta + (size_t)b * N0;  // (t,p) pairs
    const long long obase = (long long)b * (DIM * RANK);

    // 3*8*64*16 = 24576 B  +  7*2*64*16 = 14336 B  -> 38912 B (4 blocks/CU)
    __shared__ float4 trigT[NBUF][TILE][64];
    __shared__ float4 pipe[NW - 1][2][64];    // [boundary][pair parity][col] = {V0,V1}

    const int jbase = 8 * w;

    // named accumulators (never runtime-indexed -> never scratch)
    float Ax0 = 0.f, Ay0 = 0.f, Ax1 = 0.f, Ay1 = 0.f;
    float Ax2 = 0.f, Ay2 = 0.f, Ax3 = 0.f, Ay3 = 0.f;
    float Ax4 = 0.f, Ay4 = 0.f, Ax5 = 0.f, Ay5 = 0.f;
    float Ax6 = 0.f, Ay6 = 0.f, Ax7 = 0.f, Ay7 = 0.f;

    // hoisted per-scan activity predicates (v_cmp once -> SGPR-pair masks)
    const bool act0 = (c >= 64 - (jbase + 0));   // j=0 -> all false on wave 0
    const bool act1 = (c >= 64 - (jbase + 1));
    const bool act2 = (c >= 64 - (jbase + 2));
    const bool act3 = (c >= 64 - (jbase + 3));
    const bool act4 = (c >= 64 - (jbase + 4));
    const bool act5 = (c >= 64 - (jbase + 5));
    const bool act6 = (c >= 64 - (jbase + 6));
    const bool act7 = (c >= 64 - (jbase + 7));

    // per-lane trig-gather byte offset within a row-pair window:
    //   lane l -> comp (l&3), scan jbase+((l>>2)&7), row (l>>5)
    // lanes 0..31 hit 32 distinct banks; lanes 32..63 alias them 2-way (free, m136)
    const int gath = ((c >> 5) << 10) + (jbase << 4) + ((c & 31) << 2);

    // staging ownership: thread -> (row rS of tile, segment jS); 512 thr = 8x64
    const int jS   = c;
    const int rS   = w;
    const int offS = NSEG0 * jS + ((jS * (jS - 1)) >> 1);
    const int lenS = NSEG0 + jS;

    // rowJ generator state (band 0; lane c <-> segment 63-c)
    const int gseg = 63 - c;
    float S = 1.f, Er = 1.f, Ei = 0.f;

    // prefetch theta for tile 0 (row rS < 192 always valid)
    float2 pf = tb[offS + rS];

    const char* ldsT = (const char*)trigT;

    #pragma unroll 1
    for (int Sm = 0; Sm < NMACRO; ++Sm) {
        // ---- stage one 8-row trig tile per macro-step, from prefetched regs ----
        if (Sm < 32) {
            const int i = (Sm << 3) + rS;          // global row this thread stages
            float4 val;
            if (i < lenS) {
                val = make_float4(__cosf(pf.x), __sinf(pf.x),
                                  __cosf(pf.y), __sinf(pf.y));
            } else if (i == lenS) {
                val = make_float4(1.f, 0.f, 1.f, 0.f);     // deposit row
            } else {
                val = make_float4(0.f, -1.f, 1.f, 0.f);    // dead row
            }
            trigT[Sm % NBUF][rS][jS] = val;
            const int i2 = i + TILE;               // prefetch next tile's theta
            if (i2 < lenS && Sm + 1 < 32) pf = tb[offS + i2];
        }

        #pragma unroll
        for (int u = 0; u < 4; ++u) {
            const int s = (Sm << 2) + u;
            BAR();                                 // the step boundary

            const int q = s - w;                   // this band's row-pair index
            if (q >= 0 && q < HSTEP) {             // wave-uniform branch
                const int i0 = q << 1;             // even row of the pair
                const int rowbase =
                    ((((i0 >> 3) % NBUF) * TILE + (i0 & 7))) * ROWB;

                // ---- single b32 gather: all 64 trig floats this wave needs ----
                const float tvf = *(const float*)(ldsT + rowbase + gath);

                // ---- values entering this band (2 rows) ----
                float V0x, V0y, V1x, V1y;
                if (w == 0) {
                    const char* gp = ldsT + (rowbase + (gseg << 4));
                    const float4 g0 = *(const float4*)gp;
                    const float4 g1 = *(const float4*)(gp + ROWB);
                    {   // row i0
                        const float Fr = Er * g0.z + Ei * g0.w;   // E * conj(e_i)
                        const float Fi = Ei * g0.z - Er * g0.w;
                        const float amp = g0.x * S;
                        V0x = amp * Fr; V0y = amp * Fi;
                        S *= g0.y;
                        const float nEr = Er * g0.z - Ei * g0.w;  // E *= e_i
                        const float nEi = Ei * g0.z + Er * g0.w;
                        Er = nEr; Ei = nEi;
                    }
                    {   // row i0+1
                        const float Fr = Er * g1.z + Ei * g1.w;
                        const float Fi = Ei * g1.z - Er * g1.w;
                        const float amp = g1.x * S;
                        V1x = amp * Fr; V1y = amp * Fi;
                        S *= g1.y;
                        const float nEr = Er * g1.z - Ei * g1.w;
                        const float nEi = Ei * g1.z + Er * g1.w;
                        Er = nEr; Ei = nEi;
                    }
                } else {
                    const float4 pv = pipe[w - 1][q & 1][c];
                    V0x = pv.x; V0y = pv.y; V1x = pv.z; V1y = pv.w;
                }

                // ---- 8 scans x 2 rows: readlane->SGPR trig, exec-guarded rot ----
                STEPK(0) STEPK(1) STEPK(2) STEPK(3)
                STEPK(4) STEPK(5) STEPK(6) STEPK(7)

                // ---- pass pair to next band / emit real parts ----
                if (w < NW - 1) {
                    pipe[w][q & 1][c] = make_float4(V0x, V0y, V1x, V1y);
                } else {
                    const long long oidx = obase + (long long)i0 * RANK + c;
                    if (oidx < out_limit)        out[oidx]        = V0x;
                    if (oidx + RANK < out_limit) out[oidx + RANK] = V1x;
                }
            }
        }
    }
}

extern "C" void kernel_launch(void* const* d_in, const int* in_sizes, int n_in,
                              void* d_out, int out_size, void* d_ws, size_t ws_size,
                              hipStream_t stream)
{
    const float* theta = (const float*)d_in[0];
    float* out = (float*)d_out;
    const int batch = in_sizes[0] / (2 * N0);        // 1024 for this problem
    if (batch <= 0) return;

    stiefel_pipe<<<batch, 64 * NW, 0, stream>>>(theta, out, (long long)out_size);
}